// Round 3
// baseline (435.310 us; speedup 1.0000x reference)
//
#include <hip/hip_runtime.h>
#include <hip/hip_bf16.h>

// Problem (fp32 in / fp32 out): out = (Q K^T) V * scale, softmax discarded.
// Associativity: out_i = Q_i @ (K_i^T @ V_i) * scale over the 32 blocks of
// 2048 rows of the flat (65536, 64) view of the (4096, 1024) projections.
// Block i == projection rows [128*i, 128*(i+1)).

#define E_DIM 1024
#define N_ROWS 4096   // b*s = 2*2048
#define TM 128
#define TN 128
#define TK 32

// ws layout (floats):
//   Q: [0,        4194304)
//   K: [4194304,  8388608)
//   V: [8388608, 12582912)
//   P: [12582912, 13631488)   // 256 partial T blocks (32 blk x 8 chunks) x 4096
//   T: [13631488, 13762560)   // 32 x 64 x 64
#define Q_OFF 0
#define K_OFF 4194304
#define V_OFF 8388608
#define P_OFF 12582912
#define T_OFF 13631488

// ---------------------------------------------------------------------------
// Kernel A: Y = x @ W^T + b for W in {Wq, Wk, Wv} (blockIdx.z selects).
// 128x128 tile / wg, TK=32, 8x8 acc per thread, transposed LDS tiles.
// ---------------------------------------------------------------------------
__global__ __launch_bounds__(256, 2) void qkv_gemm_f32(
    const float* __restrict__ x,
    const float* __restrict__ Wq, const float* __restrict__ bq,
    const float* __restrict__ Wk, const float* __restrict__ bk,
    const float* __restrict__ Wv, const float* __restrict__ bv,
    float* __restrict__ ws)
{
    const int which = blockIdx.z;
    const float* __restrict__ W    = (which == 0) ? Wq : (which == 1) ? Wk : Wv;
    const float* __restrict__ bias = (which == 0) ? bq : (which == 1) ? bk : bv;
    float* __restrict__ Y = ws + (size_t)which * ((size_t)N_ROWS * E_DIM);

    __shared__ float Xs[TK][TM + 4];   // Xs[k][m] = x[m0+m][k0+k]
    __shared__ float Wsm[TK][TN + 4];  // Wsm[k][n] = W[n0+n][k0+k]

    const int tid = threadIdx.x;
    const int tx = tid & 15;   // -> n
    const int ty = tid >> 4;   // -> m
    const int m0 = blockIdx.x * TM;
    const int n0 = blockIdx.y * TN;

    float acc[8][8];
    #pragma unroll
    for (int i = 0; i < 8; ++i)
        #pragma unroll
        for (int j = 0; j < 8; ++j) acc[i][j] = 0.0f;

    for (int k0 = 0; k0 < E_DIM; k0 += TK) {
        // Stage 128x32 tiles of x and W (both dotted along contiguous e axis).
        #pragma unroll
        for (int l = 0; l < 4; ++l) {
            const int idx = tid + 256 * l;    // 0..1023
            const int r  = idx >> 3;          // 0..127
            const int c4 = idx & 7;           // 0..7 (float4 col)
            const float4 vx = *(const float4*)(x + (size_t)(m0 + r) * E_DIM + (k0 + c4 * 4));
            Xs[c4 * 4 + 0][r] = vx.x;
            Xs[c4 * 4 + 1][r] = vx.y;
            Xs[c4 * 4 + 2][r] = vx.z;
            Xs[c4 * 4 + 3][r] = vx.w;
            const float4 vw = *(const float4*)(W + (size_t)(n0 + r) * E_DIM + (k0 + c4 * 4));
            Wsm[c4 * 4 + 0][r] = vw.x;
            Wsm[c4 * 4 + 1][r] = vw.y;
            Wsm[c4 * 4 + 2][r] = vw.z;
            Wsm[c4 * 4 + 3][r] = vw.w;
        }
        __syncthreads();
        #pragma unroll
        for (int kk = 0; kk < TK; ++kk) {
            float a[8], b[8];
            *(float4*)&a[0] = *(const float4*)&Xs[kk][ty * 8];
            *(float4*)&a[4] = *(const float4*)&Xs[kk][ty * 8 + 4];
            *(float4*)&b[0] = *(const float4*)&Wsm[kk][tx * 8];
            *(float4*)&b[4] = *(const float4*)&Wsm[kk][tx * 8 + 4];
            #pragma unroll
            for (int i = 0; i < 8; ++i)
                #pragma unroll
                for (int j = 0; j < 8; ++j)
                    acc[i][j] = fmaf(a[i], b[j], acc[i][j]);
        }
        __syncthreads();
    }

    float bj[8];
    #pragma unroll
    for (int j = 0; j < 8; ++j) bj[j] = bias[n0 + tx * 8 + j];

    #pragma unroll
    for (int i = 0; i < 8; ++i) {
        const int row = m0 + ty * 8 + i;
        float4 o0, o1;
        o0.x = acc[i][0] + bj[0]; o0.y = acc[i][1] + bj[1];
        o0.z = acc[i][2] + bj[2]; o0.w = acc[i][3] + bj[3];
        o1.x = acc[i][4] + bj[4]; o1.y = acc[i][5] + bj[5];
        o1.z = acc[i][6] + bj[6]; o1.w = acc[i][7] + bj[7];
        float* yrow = Y + (size_t)row * E_DIM + n0 + tx * 8;
        *(float4*)(yrow)     = o0;
        *(float4*)(yrow + 4) = o1;
    }
}

// ---------------------------------------------------------------------------
// Kernel B: partial T: for block i (32), chunk c (8 x 256 rows):
//   P[i*8+c][e][d] = sum_{r in chunk} K[i][r][e] * V[i][r][d]
// ---------------------------------------------------------------------------
__global__ __launch_bounds__(256) void kT_partial(
    const float* __restrict__ ws, float* __restrict__ P)
{
    const size_t base = (size_t)blockIdx.x * (2048 * 64) + (size_t)blockIdx.y * (256 * 64);
    const float* __restrict__ Kb = ws + K_OFF + base;
    const float* __restrict__ Vb = ws + V_OFF + base;
    float* __restrict__ Pout = P + ((size_t)blockIdx.x * 8 + blockIdx.y) * 4096;

    __shared__ float Ks[32][64];
    __shared__ float Vs[32][64];

    const int tid = threadIdx.x;
    const int d  = tid & 63;
    const int eg = tid >> 6;   // 0..3 -> e group of 16

    float acc[16];
    #pragma unroll
    for (int j = 0; j < 16; ++j) acc[j] = 0.0f;

    for (int rc = 0; rc < 256; rc += 32) {
        #pragma unroll
        for (int l = 0; l < 2; ++l) {
            const int idx = tid + 256 * l;   // 0..511
            const int r  = idx >> 4;         // 0..31
            const int c4 = idx & 15;         // 0..15
            *(float4*)&Ks[r][c4 * 4] = *(const float4*)(Kb + (size_t)(rc + r) * 64 + c4 * 4);
            *(float4*)&Vs[r][c4 * 4] = *(const float4*)(Vb + (size_t)(rc + r) * 64 + c4 * 4);
        }
        __syncthreads();
        #pragma unroll
        for (int r = 0; r < 32; ++r) {
            const float v = Vs[r][d];
            #pragma unroll
            for (int j = 0; j < 16; ++j)
                acc[j] = fmaf(Ks[r][eg * 16 + j], v, acc[j]);
        }
        __syncthreads();
    }
    #pragma unroll
    for (int j = 0; j < 16; ++j)
        Pout[(size_t)(eg * 16 + j) * 64 + d] = acc[j];
}

// ---------------------------------------------------------------------------
// Kernel C0: reduce 8 partials -> T[32][64][64]
// ---------------------------------------------------------------------------
__global__ __launch_bounds__(256) void reduce_T(
    const float* __restrict__ P, float* __restrict__ T)
{
    const int idx = blockIdx.x * 256 + threadIdx.x;  // 0..131071
    const int i   = idx >> 12;
    const int off = idx & 4095;
    const float* p = P + (size_t)i * 8 * 4096 + off;
    float s = 0.0f;
    #pragma unroll
    for (int c = 0; c < 8; ++c) s += p[(size_t)c * 4096];
    T[idx] = s;
}

// ---------------------------------------------------------------------------
// Kernel C: out[r][d] = scale * sum_e Q[r][e] * T_{r>>11}[e][d], r in [0,65536)
// One wave per proj row rr (r = rr*16 + h); lane = d; T column in registers.
// fp32 output (reference output dtype is float32).
// ---------------------------------------------------------------------------
__global__ __launch_bounds__(256) void qT_out(
    const float* __restrict__ ws, float* __restrict__ out)
{
    const float* __restrict__ Q = ws + Q_OFF;
    const float* __restrict__ T = ws + T_OFF;
    const int rr0  = blockIdx.x * 16;
    const int blk  = rr0 >> 7;
    const int w    = threadIdx.x >> 6;
    const int lane = threadIdx.x & 63;

    // T column d=lane into registers: Treg[e] = T_blk[e][lane]
    float Treg[64];
    const float* Tb = T + (size_t)blk * 4096;
    #pragma unroll
    for (int e = 0; e < 64; ++e) Treg[e] = Tb[(size_t)e * 64 + lane];

    __shared__ float Qs[4][1024];

    for (int rl = 0; rl < 4; ++rl) {
        const int rr = rr0 + w * 4 + rl;
        // stage Q row rr (wave-private LDS buffer)
        #pragma unroll
        for (int t = 0; t < 4; ++t) {
            const int f = lane + 64 * t;   // float4 index 0..255
            *(float4*)&Qs[w][f * 4] = *(const float4*)(Q + (size_t)rr * 1024 + f * 4);
        }
        __syncthreads();   // uniform across all waves
        #pragma unroll
        for (int h = 0; h < 16; ++h) {
            float acc = 0.0f;
            #pragma unroll
            for (int e4 = 0; e4 < 16; ++e4) {
                const float4 q = *(const float4*)&Qs[w][h * 64 + e4 * 4];
                acc = fmaf(q.x, Treg[e4 * 4 + 0], acc);
                acc = fmaf(q.y, Treg[e4 * 4 + 1], acc);
                acc = fmaf(q.z, Treg[e4 * 4 + 2], acc);
                acc = fmaf(q.w, Treg[e4 * 4 + 3], acc);
            }
            out[(size_t)(rr * 16 + h) * 64 + lane] = 0.125f * acc;
        }
        __syncthreads();
    }
}

extern "C" void kernel_launch(void* const* d_in, const int* in_sizes, int n_in,
                              void* d_out, int out_size, void* d_ws, size_t ws_size,
                              hipStream_t stream)
{
    const float* x  = (const float*)d_in[0];
    const float* Wq = (const float*)d_in[1];
    const float* bq = (const float*)d_in[2];
    const float* Wk = (const float*)d_in[3];
    const float* bk = (const float*)d_in[4];
    const float* Wv = (const float*)d_in[5];
    const float* bv = (const float*)d_in[6];
    float* ws = (float*)d_ws;
    float* out = (float*)d_out;

    dim3 gA(N_ROWS / TM, E_DIM / TN, 3);     // 32 x 8 x 3
    qkv_gemm_f32<<<gA, 256, 0, stream>>>(x, Wq, bq, Wk, bk, Wv, bv, ws);

    dim3 gB(32, 8);
    kT_partial<<<gB, 256, 0, stream>>>(ws, ws + P_OFF);

    reduce_T<<<512, 256, 0, stream>>>(ws + P_OFF, ws + T_OFF);

    qT_out<<<256, 256, 0, stream>>>(ws, out);
}

// Round 4
// 180.017 us; speedup vs baseline: 2.4182x; 2.4182x over previous
//
#include <hip/hip_runtime.h>
#include <hip/hip_bf16.h>

// out = (Q K^T) V * scale, softmax discarded => associativity:
//   out_i = Q_i @ (K_i^T @ V_i) * scale, 32 blocks of 2048 rows of the flat
//   (65536,64) view of the (4096,1024) projections.
// R4: projections via bf16 MFMA (16x16x32), fp32 accumulate. Q/K/V stored bf16.

#define E_DIM 1024
#define N_ROWS 4096

typedef __attribute__((ext_vector_type(8))) short bf16x8;
typedef __attribute__((ext_vector_type(4))) float f32x4;

// ---- ws layout ----
// ushort indices (bf16 regions):
//   QB 0 .. 4194304, KB .. 8388608, VB .. 12582912
//   XB 12582912 .. 16777216   (x as bf16, 4096x1024)
//   WB 16777216 .. 19922944   (Wq,Wk,Wv as bf16, 3x1024x1024)
// float indices (fp32 regions):
//   P 9961472 .. 11010048, T 11010048 .. 11141120      (total ws 44.6 MB)
#define QB_U 0
#define KB_U 4194304
#define VB_U 8388608
#define XB_U 12582912
#define WB_U 16777216
#define P_F  9961472
#define T_F  11010048

__device__ __forceinline__ unsigned short f2b(float f) {
    union { float f; unsigned int i; } c; c.f = f;
    unsigned int r = c.i + 0x7FFFu + ((c.i >> 16) & 1u);   // RNE (finite data)
    return (unsigned short)(r >> 16);
}
__device__ __forceinline__ float blo(unsigned int u) {
    union { unsigned int i; float f; } c; c.i = u << 16; return c.f;
}
__device__ __forceinline__ float bhi(unsigned int u) {
    union { unsigned int i; float f; } c; c.i = u & 0xFFFF0000u; return c.f;
}

typedef __attribute__((address_space(1))) const void* gptr_t;
typedef __attribute__((address_space(3))) void* lptr_t;
__device__ __forceinline__ void gl_lds16(const void* g, void* l) {
    __builtin_amdgcn_global_load_lds((gptr_t)g, (lptr_t)l, 16, 0, 0);
}

// ---------------------------------------------------------------------------
// Kernel 0: fp32 -> bf16 convert. 7 segments of 1M elems: x(4) + Wq/Wk/Wv.
// dst = XB (x) then WB (weights), contiguous.
// ---------------------------------------------------------------------------
__global__ __launch_bounds__(256) void cvt_bf16(
    const float* __restrict__ x,  const float* __restrict__ wq,
    const float* __restrict__ wk, const float* __restrict__ wv,
    unsigned short* __restrict__ dst0)
{
    const int seg = blockIdx.y;
    const float* __restrict__ src;
    unsigned short* __restrict__ dst;
    if (seg < 4) { src = x + (size_t)seg * 1048576; dst = dst0 + (size_t)seg * 1048576; }
    else {
        src = (seg == 4) ? wq : (seg == 5) ? wk : wv;
        dst = dst0 + 4194304 + (size_t)(seg - 4) * 1048576;
    }
    const int i = blockIdx.x * 256 + threadIdx.x;   // 0..131071
    const float4 a = *(const float4*)(src + (size_t)i * 8);
    const float4 b = *(const float4*)(src + (size_t)i * 8 + 4);
    uint4 o;
    o.x = (unsigned)f2b(a.x) | ((unsigned)f2b(a.y) << 16);
    o.y = (unsigned)f2b(a.z) | ((unsigned)f2b(a.w) << 16);
    o.z = (unsigned)f2b(b.x) | ((unsigned)f2b(b.y) << 16);
    o.w = (unsigned)f2b(b.z) | ((unsigned)f2b(b.w) << 16);
    *(uint4*)(dst + (size_t)i * 8) = o;
}

// ---------------------------------------------------------------------------
// Kernel A: Y(bf16) = Xb @ Wb^T + bias, per weight (blockIdx.z).
// m97 structure: 128x128 tile, BK=32, global_load_lds x16, 16x16x32 bf16 MFMA,
// 4 waves x (4x4 tiles of 16x16), fp32 acc, bf16 store.
// ---------------------------------------------------------------------------
__global__ __launch_bounds__(256, 2) void qkv_gemm_mfma(
    const unsigned short* __restrict__ Xb,   // [4096][1024] bf16
    const unsigned short* __restrict__ Wb,   // [3][1024][1024] bf16
    const float* __restrict__ bq, const float* __restrict__ bk,
    const float* __restrict__ bv,
    unsigned short* __restrict__ qkv)        // QB/KB/VB bf16
{
    const int which = blockIdx.z;
    const unsigned short* __restrict__ W = Wb + (size_t)which * (1024 * 1024);
    const float* __restrict__ bias = (which == 0) ? bq : (which == 1) ? bk : bv;
    unsigned short* __restrict__ Y = qkv + (size_t)which * ((size_t)N_ROWS * E_DIM);

    __shared__ __align__(16) unsigned short Als[128 * 32];  // [row][k], 64B rows
    __shared__ __align__(16) unsigned short Bls[128 * 32];

    const int tid  = threadIdx.x;
    const int w    = tid >> 6;
    const int lane = tid & 63;
    const int m0 = blockIdx.x * 128;
    const int n0 = blockIdx.y * 128;
    const int wm = (w >> 1) * 64;     // wave row origin in tile
    const int wn = (w & 1) * 64;      // wave col origin in tile

    f32x4 acc[4][4];
    #pragma unroll
    for (int i = 0; i < 4; ++i)
        #pragma unroll
        for (int j = 0; j < 4; ++j)
            acc[i][j] = f32x4{0.f, 0.f, 0.f, 0.f};

    // staging geometry: chunk c = w*2+j covers rows [16c,16c+16); lane -> row
    // 16c + lane/4, k-chunk (lane&3)*8. LDS dst = chunk base + lane*16 B.
    const int srow = w * 32 + (lane >> 2);
    const int skc  = (lane & 3) * 8;
    const int kq   = (lane >> 4) * 8;     // fragment k offset (quad*8)
    const int fm   = lane & 15;           // fragment row/col within 16

    for (int k0 = 0; k0 < E_DIM; k0 += 32) {
        gl_lds16((const void*)(Xb + (size_t)(m0 + srow) * E_DIM + k0 + skc),
                 (void*)((char*)Als + (w * 2 + 0) * 1024));
        gl_lds16((const void*)(Xb + (size_t)(m0 + srow + 16) * E_DIM + k0 + skc),
                 (void*)((char*)Als + (w * 2 + 1) * 1024));
        gl_lds16((const void*)(W + (size_t)(n0 + srow) * E_DIM + k0 + skc),
                 (void*)((char*)Bls + (w * 2 + 0) * 1024));
        gl_lds16((const void*)(W + (size_t)(n0 + srow + 16) * E_DIM + k0 + skc),
                 (void*)((char*)Bls + (w * 2 + 1) * 1024));
        __syncthreads();

        bf16x8 af[4], bf[4];
        #pragma unroll
        for (int t = 0; t < 4; ++t) {
            af[t] = *(const bf16x8*)(Als + (wm + t * 16 + fm) * 32 + kq);
            bf[t] = *(const bf16x8*)(Bls + (wn + t * 16 + fm) * 32 + kq);
        }
        #pragma unroll
        for (int rt = 0; rt < 4; ++rt)
            #pragma unroll
            for (int ct = 0; ct < 4; ++ct)
                acc[rt][ct] = __builtin_amdgcn_mfma_f32_16x16x32_bf16(
                    af[rt], bf[ct], acc[rt][ct], 0, 0, 0);
        __syncthreads();
    }

    // epilogue: C/D layout col = lane&15, row = (lane>>4)*4 + reg
    float bcol[4];
    #pragma unroll
    for (int ct = 0; ct < 4; ++ct) bcol[ct] = bias[n0 + wn + ct * 16 + fm];

    const int rbase = (lane >> 4) * 4;
    #pragma unroll
    for (int rt = 0; rt < 4; ++rt) {
        #pragma unroll
        for (int ct = 0; ct < 4; ++ct) {
            #pragma unroll
            for (int r = 0; r < 4; ++r) {
                const int row = m0 + wm + rt * 16 + rbase + r;
                const int col = n0 + wn + ct * 16 + fm;
                Y[(size_t)row * E_DIM + col] = f2b(acc[rt][ct][r] + bcol[ct]);
            }
        }
    }
}

// ---------------------------------------------------------------------------
// Kernel B: partial T from bf16 K,V (fp32 math):
//   P[i*8+c][e][d] = sum_{r in 256-row chunk} K[i][r][e] * V[i][r][d]
// ---------------------------------------------------------------------------
__global__ __launch_bounds__(256) void kT_partial(
    const unsigned short* __restrict__ qkv, float* __restrict__ P)
{
    const size_t base = (size_t)blockIdx.x * (2048 * 64) + (size_t)blockIdx.y * (256 * 64);
    const unsigned short* __restrict__ Kb = qkv + KB_U + base;
    const unsigned short* __restrict__ Vb = qkv + VB_U + base;
    float* __restrict__ Pout = P + ((size_t)blockIdx.x * 8 + blockIdx.y) * 4096;

    __shared__ float Ks[32][64];
    __shared__ float Vs[32][64];

    const int tid = threadIdx.x;
    const int d  = tid & 63;
    const int eg = tid >> 6;

    float acc[16];
    #pragma unroll
    for (int j = 0; j < 16; ++j) acc[j] = 0.0f;

    const int sr = tid >> 3;        // 0..31
    const int sc = (tid & 7) * 8;   // elem col

    for (int rc = 0; rc < 256; rc += 32) {
        const uint4 ku = *(const uint4*)(Kb + (size_t)(rc + sr) * 64 + sc);
        const uint4 vu = *(const uint4*)(Vb + (size_t)(rc + sr) * 64 + sc);
        Ks[sr][sc + 0] = blo(ku.x); Ks[sr][sc + 1] = bhi(ku.x);
        Ks[sr][sc + 2] = blo(ku.y); Ks[sr][sc + 3] = bhi(ku.y);
        Ks[sr][sc + 4] = blo(ku.z); Ks[sr][sc + 5] = bhi(ku.z);
        Ks[sr][sc + 6] = blo(ku.w); Ks[sr][sc + 7] = bhi(ku.w);
        Vs[sr][sc + 0] = blo(vu.x); Vs[sr][sc + 1] = bhi(vu.x);
        Vs[sr][sc + 2] = blo(vu.y); Vs[sr][sc + 3] = bhi(vu.y);
        Vs[sr][sc + 4] = blo(vu.z); Vs[sr][sc + 5] = bhi(vu.z);
        Vs[sr][sc + 6] = blo(vu.w); Vs[sr][sc + 7] = bhi(vu.w);
        __syncthreads();
        #pragma unroll
        for (int r = 0; r < 32; ++r) {
            const float v = Vs[r][d];
            #pragma unroll
            for (int j = 0; j < 16; ++j)
                acc[j] = fmaf(Ks[r][eg * 16 + j], v, acc[j]);
        }
        __syncthreads();
    }
    #pragma unroll
    for (int j = 0; j < 16; ++j)
        Pout[(size_t)(eg * 16 + j) * 64 + d] = acc[j];
}

// ---------------------------------------------------------------------------
// Kernel C0: reduce 8 partials -> T[32][64][64] (fp32)
// ---------------------------------------------------------------------------
__global__ __launch_bounds__(256) void reduce_T(
    const float* __restrict__ P, float* __restrict__ T)
{
    const int idx = blockIdx.x * 256 + threadIdx.x;
    const int i   = idx >> 12;
    const int off = idx & 4095;
    const float* p = P + (size_t)i * 8 * 4096 + off;
    float s = 0.0f;
    #pragma unroll
    for (int c = 0; c < 8; ++c) s += p[(size_t)c * 4096];
    T[idx] = s;
}

// ---------------------------------------------------------------------------
// Kernel C: out[r][d] = 0.125 * sum_e Q[r][e] * T_{r>>11}[e][d]  (fp32 out)
// ---------------------------------------------------------------------------
__global__ __launch_bounds__(256) void qT_out(
    const unsigned short* __restrict__ qkv, const float* __restrict__ T,
    float* __restrict__ out)
{
    const unsigned short* __restrict__ Q = qkv + QB_U;
    const int rr0  = blockIdx.x * 16;
    const int blk  = rr0 >> 7;
    const int w    = threadIdx.x >> 6;
    const int lane = threadIdx.x & 63;

    float Treg[64];
    const float* Tb = T + (size_t)blk * 4096;
    #pragma unroll
    for (int e = 0; e < 64; ++e) Treg[e] = Tb[(size_t)e * 64 + lane];

    __shared__ float Qs[4][1024];

    for (int rl = 0; rl < 4; ++rl) {
        const int rr = rr0 + w * 4 + rl;
        #pragma unroll
        for (int t = 0; t < 2; ++t) {
            const int eo = (lane + 64 * t) * 8;
            const uint4 qu = *(const uint4*)(Q + (size_t)rr * 1024 + eo);
            Qs[w][eo + 0] = blo(qu.x); Qs[w][eo + 1] = bhi(qu.x);
            Qs[w][eo + 2] = blo(qu.y); Qs[w][eo + 3] = bhi(qu.y);
            Qs[w][eo + 4] = blo(qu.z); Qs[w][eo + 5] = bhi(qu.z);
            Qs[w][eo + 6] = blo(qu.w); Qs[w][eo + 7] = bhi(qu.w);
        }
        __syncthreads();
        #pragma unroll
        for (int h = 0; h < 16; ++h) {
            float acc = 0.0f;
            #pragma unroll
            for (int e4 = 0; e4 < 16; ++e4) {
                const float4 q = *(const float4*)&Qs[w][h * 64 + e4 * 4];
                acc = fmaf(q.x, Treg[e4 * 4 + 0], acc);
                acc = fmaf(q.y, Treg[e4 * 4 + 1], acc);
                acc = fmaf(q.z, Treg[e4 * 4 + 2], acc);
                acc = fmaf(q.w, Treg[e4 * 4 + 3], acc);
            }
            out[(size_t)(rr * 16 + h) * 64 + lane] = 0.125f * acc;
        }
        __syncthreads();
    }
}

extern "C" void kernel_launch(void* const* d_in, const int* in_sizes, int n_in,
                              void* d_out, int out_size, void* d_ws, size_t ws_size,
                              hipStream_t stream)
{
    const float* x  = (const float*)d_in[0];
    const float* Wq = (const float*)d_in[1];
    const float* bq = (const float*)d_in[2];
    const float* Wk = (const float*)d_in[3];
    const float* bk = (const float*)d_in[4];
    const float* Wv = (const float*)d_in[5];
    const float* bv = (const float*)d_in[6];
    float* wsf = (float*)d_ws;
    unsigned short* wsu = (unsigned short*)d_ws;
    float* out = (float*)d_out;

    dim3 gCvt(512, 7);
    cvt_bf16<<<gCvt, 256, 0, stream>>>(x, Wq, Wk, Wv, wsu + XB_U);

    dim3 gA(N_ROWS / 128, E_DIM / 128, 3);   // 32 x 8 x 3
    qkv_gemm_mfma<<<gA, 256, 0, stream>>>(wsu + XB_U, wsu + WB_U,
                                          bq, bk, bv, wsu + QB_U);

    dim3 gB(32, 8);
    kT_partial<<<gB, 256, 0, stream>>>(wsu, wsf + P_F);

    reduce_T<<<512, 256, 0, stream>>>(wsf + P_F, wsf + T_F);

    qT_out<<<256, 256, 0, stream>>>(wsu, wsf + T_F, out);
}

// Round 5
// 140.184 us; speedup vs baseline: 3.1053x; 1.2842x over previous
//
#include <hip/hip_runtime.h>
#include <hip/hip_bf16.h>

// out = (Q K^T) V * scale, softmax discarded => associativity:
//   out_i = Q_i @ (K_i^T @ V_i) * scale over 32 blocks of 2048 flat rows of
//   the (65536,64) view of the (4096,1024) projections.
// R5: tail kernels restructured — qT as MFMA mini-GEMM vs bf16 T^T; kT split
// into 512 wgs. Projections via bf16 MFMA unchanged.

#define E_DIM 1024
#define N_ROWS 4096

typedef __attribute__((ext_vector_type(8))) short bf16x8;
typedef __attribute__((ext_vector_type(4))) float f32x4;

// ---- ws layout (bytes) ----
// QB [0,8.4M) KB [8.4,16.8M) VB [16.8,25.2M) bf16
// XB [25.2,33.6M) WB [33.6,39.8M) bf16
// P  [39.8,48.2M) fp32 (32 blk x 16 chunks x 4096)
// TB [48.2,48.5M) bf16 Tt[32][d=64][e=64]
#define QB_U 0
#define KB_U 4194304
#define VB_U 8388608
#define XB_U 12582912
#define WB_U 16777216
#define P_F  9961472
#define TB_U 24117248

__device__ __forceinline__ unsigned short f2b(float f) {
    union { float f; unsigned int i; } c; c.f = f;
    unsigned int r = c.i + 0x7FFFu + ((c.i >> 16) & 1u);   // RNE (finite data)
    return (unsigned short)(r >> 16);
}
__device__ __forceinline__ float blo(unsigned int u) {
    union { unsigned int i; float f; } c; c.i = u << 16; return c.f;
}
__device__ __forceinline__ float bhi(unsigned int u) {
    union { unsigned int i; float f; } c; c.i = u & 0xFFFF0000u; return c.f;
}

typedef __attribute__((address_space(1))) const void* gptr_t;
typedef __attribute__((address_space(3))) void* lptr_t;
__device__ __forceinline__ void gl_lds16(const void* g, void* l) {
    __builtin_amdgcn_global_load_lds((gptr_t)g, (lptr_t)l, 16, 0, 0);
}

// ---------------------------------------------------------------------------
// Kernel 0: fp32 -> bf16 convert: x (4 MB-segs) + Wq/Wk/Wv.
// ---------------------------------------------------------------------------
__global__ __launch_bounds__(256) void cvt_bf16(
    const float* __restrict__ x,  const float* __restrict__ wq,
    const float* __restrict__ wk, const float* __restrict__ wv,
    unsigned short* __restrict__ dst0)
{
    const int seg = blockIdx.y;
    const float* __restrict__ src;
    unsigned short* __restrict__ dst;
    if (seg < 4) { src = x + (size_t)seg * 1048576; dst = dst0 + (size_t)seg * 1048576; }
    else {
        src = (seg == 4) ? wq : (seg == 5) ? wk : wv;
        dst = dst0 + 4194304 + (size_t)(seg - 4) * 1048576;
    }
    const int i = blockIdx.x * 256 + threadIdx.x;   // 0..131071
    const float4 a = *(const float4*)(src + (size_t)i * 8);
    const float4 b = *(const float4*)(src + (size_t)i * 8 + 4);
    uint4 o;
    o.x = (unsigned)f2b(a.x) | ((unsigned)f2b(a.y) << 16);
    o.y = (unsigned)f2b(a.z) | ((unsigned)f2b(a.w) << 16);
    o.z = (unsigned)f2b(b.x) | ((unsigned)f2b(b.y) << 16);
    o.w = (unsigned)f2b(b.z) | ((unsigned)f2b(b.w) << 16);
    *(uint4*)(dst + (size_t)i * 8) = o;
}

// ---------------------------------------------------------------------------
// Kernel A: Y(bf16) = Xb @ Wb^T + bias (blockIdx.z selects weight).
// 128x128 tile, BK=32, global_load_lds x16, 16x16x32 bf16 MFMA, fp32 acc.
// ---------------------------------------------------------------------------
__global__ __launch_bounds__(256, 2) void qkv_gemm_mfma(
    const unsigned short* __restrict__ Xb,
    const unsigned short* __restrict__ Wb,
    const float* __restrict__ bq, const float* __restrict__ bk,
    const float* __restrict__ bv,
    unsigned short* __restrict__ qkv)
{
    const int which = blockIdx.z;
    const unsigned short* __restrict__ W = Wb + (size_t)which * (1024 * 1024);
    const float* __restrict__ bias = (which == 0) ? bq : (which == 1) ? bk : bv;
    unsigned short* __restrict__ Y = qkv + (size_t)which * ((size_t)N_ROWS * E_DIM);

    __shared__ __align__(16) unsigned short Als[128 * 32];
    __shared__ __align__(16) unsigned short Bls[128 * 32];

    const int tid  = threadIdx.x;
    const int w    = tid >> 6;
    const int lane = tid & 63;
    const int m0 = blockIdx.x * 128;
    const int n0 = blockIdx.y * 128;
    const int wm = (w >> 1) * 64;
    const int wn = (w & 1) * 64;

    f32x4 acc[4][4];
    #pragma unroll
    for (int i = 0; i < 4; ++i)
        #pragma unroll
        for (int j = 0; j < 4; ++j)
            acc[i][j] = f32x4{0.f, 0.f, 0.f, 0.f};

    const int srow = w * 32 + (lane >> 2);
    const int skc  = (lane & 3) * 8;
    const int kq   = (lane >> 4) * 8;
    const int fm   = lane & 15;

    for (int k0 = 0; k0 < E_DIM; k0 += 32) {
        gl_lds16((const void*)(Xb + (size_t)(m0 + srow) * E_DIM + k0 + skc),
                 (void*)((char*)Als + (w * 2 + 0) * 1024));
        gl_lds16((const void*)(Xb + (size_t)(m0 + srow + 16) * E_DIM + k0 + skc),
                 (void*)((char*)Als + (w * 2 + 1) * 1024));
        gl_lds16((const void*)(W + (size_t)(n0 + srow) * E_DIM + k0 + skc),
                 (void*)((char*)Bls + (w * 2 + 0) * 1024));
        gl_lds16((const void*)(W + (size_t)(n0 + srow + 16) * E_DIM + k0 + skc),
                 (void*)((char*)Bls + (w * 2 + 1) * 1024));
        __syncthreads();

        bf16x8 af[4], bf[4];
        #pragma unroll
        for (int t = 0; t < 4; ++t) {
            af[t] = *(const bf16x8*)(Als + (wm + t * 16 + fm) * 32 + kq);
            bf[t] = *(const bf16x8*)(Bls + (wn + t * 16 + fm) * 32 + kq);
        }
        #pragma unroll
        for (int rt = 0; rt < 4; ++rt)
            #pragma unroll
            for (int ct = 0; ct < 4; ++ct)
                acc[rt][ct] = __builtin_amdgcn_mfma_f32_16x16x32_bf16(
                    af[rt], bf[ct], acc[rt][ct], 0, 0, 0);
        __syncthreads();
    }

    float bcol[4];
    #pragma unroll
    for (int ct = 0; ct < 4; ++ct) bcol[ct] = bias[n0 + wn + ct * 16 + fm];

    const int rbase = (lane >> 4) * 4;
    #pragma unroll
    for (int rt = 0; rt < 4; ++rt) {
        #pragma unroll
        for (int ct = 0; ct < 4; ++ct) {
            #pragma unroll
            for (int r = 0; r < 4; ++r) {
                const int row = m0 + wm + rt * 16 + rbase + r;
                const int col = n0 + wn + ct * 16 + fm;
                Y[(size_t)row * E_DIM + col] = f2b(acc[rt][ct][r] + bcol[ct]);
            }
        }
    }
}

// ---------------------------------------------------------------------------
// Kernel B: partial T: block (i, c): 128-row chunk:
//   P[i*16+c][e*64+d] = sum_{r in chunk} K[i][r][e] * V[i][r][d]   (fp32)
// ---------------------------------------------------------------------------
__global__ __launch_bounds__(256) void kT_partial(
    const unsigned short* __restrict__ qkv, float* __restrict__ P)
{
    const size_t base = (size_t)blockIdx.x * (2048 * 64) + (size_t)blockIdx.y * (128 * 64);
    const unsigned short* __restrict__ Kb = qkv + KB_U + base;
    const unsigned short* __restrict__ Vb = qkv + VB_U + base;
    float* __restrict__ Pout = P + ((size_t)blockIdx.x * 16 + blockIdx.y) * 4096;

    __shared__ float Ks[32][64];
    __shared__ float Vs[32][64];

    const int tid = threadIdx.x;
    const int d  = tid & 63;
    const int eg = tid >> 6;

    float acc[16];
    #pragma unroll
    for (int j = 0; j < 16; ++j) acc[j] = 0.0f;

    const int sr = tid >> 3;        // 0..31
    const int sc = (tid & 7) * 8;   // elem col

    for (int rc = 0; rc < 128; rc += 32) {
        const uint4 ku = *(const uint4*)(Kb + (size_t)(rc + sr) * 64 + sc);
        const uint4 vu = *(const uint4*)(Vb + (size_t)(rc + sr) * 64 + sc);
        Ks[sr][sc + 0] = blo(ku.x); Ks[sr][sc + 1] = bhi(ku.x);
        Ks[sr][sc + 2] = blo(ku.y); Ks[sr][sc + 3] = bhi(ku.y);
        Ks[sr][sc + 4] = blo(ku.z); Ks[sr][sc + 5] = bhi(ku.z);
        Ks[sr][sc + 6] = blo(ku.w); Ks[sr][sc + 7] = bhi(ku.w);
        Vs[sr][sc + 0] = blo(vu.x); Vs[sr][sc + 1] = bhi(vu.x);
        Vs[sr][sc + 2] = blo(vu.y); Vs[sr][sc + 3] = bhi(vu.y);
        Vs[sr][sc + 4] = blo(vu.z); Vs[sr][sc + 5] = bhi(vu.z);
        Vs[sr][sc + 6] = blo(vu.w); Vs[sr][sc + 7] = bhi(vu.w);
        __syncthreads();
        #pragma unroll
        for (int r = 0; r < 32; ++r) {
            const float v = Vs[r][d];
            #pragma unroll
            for (int j = 0; j < 16; ++j)
                acc[j] = fmaf(Ks[r][eg * 16 + j], v, acc[j]);
        }
        __syncthreads();
    }
    #pragma unroll
    for (int j = 0; j < 16; ++j)
        Pout[(size_t)(eg * 16 + j) * 64 + d] = acc[j];
}

// ---------------------------------------------------------------------------
// Kernel C0: reduce 16 partials -> Tt bf16, transposed: TB[i][d][e]
// ---------------------------------------------------------------------------
__global__ __launch_bounds__(256) void reduce_T(
    const float* __restrict__ P, unsigned short* __restrict__ TB)
{
    const int idx = blockIdx.x * 256 + threadIdx.x;  // 0..131071
    const int i   = idx >> 12;
    const int off = idx & 4095;          // e*64 + d
    const float* p = P + (size_t)i * 16 * 4096 + off;
    float s = 0.0f;
    #pragma unroll
    for (int c = 0; c < 16; ++c) s += p[(size_t)c * 4096];
    const int e = off >> 6, d = off & 63;
    TB[(size_t)i * 4096 + d * 64 + e] = f2b(s);
}

// ---------------------------------------------------------------------------
// Kernel C: out = 0.125 * Qflat @ Tt^T  (MFMA mini-GEMM, K=64).
// Qflat rows (bf16, contiguous in QB) are the A operand [r][e]; Tt rows
// (bf16, [d][e]) are the B operand. 512 wgs x 128 flat rows. fp32 out.
// ---------------------------------------------------------------------------
__global__ __launch_bounds__(256, 2) void qT_mfma(
    const unsigned short* __restrict__ qkv,
    const unsigned short* __restrict__ TB,
    float* __restrict__ out)
{
    __shared__ __align__(16) unsigned short Als[128 * 64];  // 16 KB: Q rows
    __shared__ __align__(16) unsigned short Bls[64 * 64];   //  8 KB: Tt rows

    const int bx   = blockIdx.x;        // 0..511
    const int r0   = bx * 128;          // flat row base
    const int i    = bx >> 4;           // attention block
    const int tid  = threadIdx.x;
    const int w    = tid >> 6;
    const int lane = tid & 63;
    const int kq   = (lane >> 4) * 8;
    const int fm   = lane & 15;

    const unsigned short* __restrict__ Qb = qkv + QB_U + (size_t)r0 * 64;
    const unsigned short* __restrict__ Tb = TB + (size_t)i * 4096;

    // Stage A: contiguous 16 KB (4 calls/wave); B: contiguous 8 KB (2/wave).
    #pragma unroll
    for (int c = 0; c < 4; ++c)
        gl_lds16((const void*)(Qb + (w * 4 + c) * 512 + lane * 8),
                 (void*)((char*)Als + (w * 4 + c) * 1024));
    #pragma unroll
    for (int c = 0; c < 2; ++c)
        gl_lds16((const void*)(Tb + (w * 2 + c) * 512 + lane * 8),
                 (void*)((char*)Bls + (w * 2 + c) * 1024));
    __syncthreads();

    // Wave w: rows [w*32, w*32+32) -> 2 m-tiles x 4 n-tiles, K=64 (2 halves).
    bf16x8 af[2][2], bf[4][2];
    #pragma unroll
    for (int mt = 0; mt < 2; ++mt)
        #pragma unroll
        for (int kk = 0; kk < 2; ++kk)
            af[mt][kk] = *(const bf16x8*)(Als + (w * 32 + mt * 16 + fm) * 64 + kk * 32 + kq);
    #pragma unroll
    for (int nt = 0; nt < 4; ++nt)
        #pragma unroll
        for (int kk = 0; kk < 2; ++kk)
            bf[nt][kk] = *(const bf16x8*)(Bls + (nt * 16 + fm) * 64 + kk * 32 + kq);

    f32x4 acc[2][4];
    #pragma unroll
    for (int mt = 0; mt < 2; ++mt)
        #pragma unroll
        for (int nt = 0; nt < 4; ++nt)
            acc[mt][nt] = f32x4{0.f, 0.f, 0.f, 0.f};

    #pragma unroll
    for (int kk = 0; kk < 2; ++kk)
        #pragma unroll
        for (int mt = 0; mt < 2; ++mt)
            #pragma unroll
            for (int nt = 0; nt < 4; ++nt)
                acc[mt][nt] = __builtin_amdgcn_mfma_f32_16x16x32_bf16(
                    af[mt][kk], bf[nt][kk], acc[mt][nt], 0, 0, 0);

    const int rbase = (lane >> 4) * 4;
    #pragma unroll
    for (int mt = 0; mt < 2; ++mt) {
        #pragma unroll
        for (int nt = 0; nt < 4; ++nt) {
            #pragma unroll
            for (int r = 0; r < 4; ++r) {
                const int row = r0 + w * 32 + mt * 16 + rbase + r;
                const int col = nt * 16 + fm;
                out[(size_t)row * 64 + col] = 0.125f * acc[mt][nt][r];
            }
        }
    }
}

extern "C" void kernel_launch(void* const* d_in, const int* in_sizes, int n_in,
                              void* d_out, int out_size, void* d_ws, size_t ws_size,
                              hipStream_t stream)
{
    const float* x  = (const float*)d_in[0];
    const float* Wq = (const float*)d_in[1];
    const float* bq = (const float*)d_in[2];
    const float* Wk = (const float*)d_in[3];
    const float* bk = (const float*)d_in[4];
    const float* Wv = (const float*)d_in[5];
    const float* bv = (const float*)d_in[6];
    float* wsf = (float*)d_ws;
    unsigned short* wsu = (unsigned short*)d_ws;
    float* out = (float*)d_out;

    dim3 gCvt(512, 7);
    cvt_bf16<<<gCvt, 256, 0, stream>>>(x, Wq, Wk, Wv, wsu + XB_U);

    dim3 gA(N_ROWS / 128, E_DIM / 128, 3);   // 32 x 8 x 3
    qkv_gemm_mfma<<<gA, 256, 0, stream>>>(wsu + XB_U, wsu + WB_U,
                                          bq, bk, bv, wsu + QB_U);

    dim3 gB(32, 16);
    kT_partial<<<gB, 256, 0, stream>>>(wsu, wsf + P_F);

    reduce_T<<<512, 256, 0, stream>>>(wsf + P_F, wsu + TB_U);

    qT_mfma<<<512, 256, 0, stream>>>(wsu, wsu + TB_U, out);
}

// Round 6
// 137.661 us; speedup vs baseline: 3.1622x; 1.0183x over previous
//
#include <hip/hip_runtime.h>
#include <hip/hip_bf16.h>

// out = (Q K^T) V * scale, softmax discarded => associativity:
//   out_i = Q_i @ (K_i^T @ V_i) * scale over 32 blocks of 2048 flat rows of
//   the (65536,64) view of the (4096,1024) projections.
// R6: qkv_gemm __launch_bounds__(256,3) so all 768 wgs (3/CU) are co-resident
// (previously min-waves=2 capped residency at 2 wgs/CU -> 1.5 rounds).

#define E_DIM 1024
#define N_ROWS 4096

typedef __attribute__((ext_vector_type(8))) short bf16x8;
typedef __attribute__((ext_vector_type(4))) float f32x4;

// ---- ws layout (bytes) ----
// QB [0,8.4M) KB [8.4,16.8M) VB [16.8,25.2M) bf16
// XB [25.2,33.6M) WB [33.6,39.8M) bf16
// P  [39.8,48.2M) fp32 (32 blk x 16 chunks x 4096)
// TB [48.2,48.5M) bf16 Tt[32][d=64][e=64]
#define QB_U 0
#define KB_U 4194304
#define VB_U 8388608
#define XB_U 12582912
#define WB_U 16777216
#define P_F  9961472
#define TB_U 24117248

__device__ __forceinline__ unsigned short f2b(float f) {
    union { float f; unsigned int i; } c; c.f = f;
    unsigned int r = c.i + 0x7FFFu + ((c.i >> 16) & 1u);   // RNE (finite data)
    return (unsigned short)(r >> 16);
}
__device__ __forceinline__ float blo(unsigned int u) {
    union { unsigned int i; float f; } c; c.i = u << 16; return c.f;
}
__device__ __forceinline__ float bhi(unsigned int u) {
    union { unsigned int i; float f; } c; c.i = u & 0xFFFF0000u; return c.f;
}

typedef __attribute__((address_space(1))) const void* gptr_t;
typedef __attribute__((address_space(3))) void* lptr_t;
__device__ __forceinline__ void gl_lds16(const void* g, void* l) {
    __builtin_amdgcn_global_load_lds((gptr_t)g, (lptr_t)l, 16, 0, 0);
}

// ---------------------------------------------------------------------------
// Kernel 0: fp32 -> bf16 convert: x (4 MB-segs) + Wq/Wk/Wv.
// ---------------------------------------------------------------------------
__global__ __launch_bounds__(256) void cvt_bf16(
    const float* __restrict__ x,  const float* __restrict__ wq,
    const float* __restrict__ wk, const float* __restrict__ wv,
    unsigned short* __restrict__ dst0)
{
    const int seg = blockIdx.y;
    const float* __restrict__ src;
    unsigned short* __restrict__ dst;
    if (seg < 4) { src = x + (size_t)seg * 1048576; dst = dst0 + (size_t)seg * 1048576; }
    else {
        src = (seg == 4) ? wq : (seg == 5) ? wk : wv;
        dst = dst0 + 4194304 + (size_t)(seg - 4) * 1048576;
    }
    const int i = blockIdx.x * 256 + threadIdx.x;   // 0..131071
    const float4 a = *(const float4*)(src + (size_t)i * 8);
    const float4 b = *(const float4*)(src + (size_t)i * 8 + 4);
    uint4 o;
    o.x = (unsigned)f2b(a.x) | ((unsigned)f2b(a.y) << 16);
    o.y = (unsigned)f2b(a.z) | ((unsigned)f2b(a.w) << 16);
    o.z = (unsigned)f2b(b.x) | ((unsigned)f2b(b.y) << 16);
    o.w = (unsigned)f2b(b.z) | ((unsigned)f2b(b.w) << 16);
    *(uint4*)(dst + (size_t)i * 8) = o;
}

// ---------------------------------------------------------------------------
// Kernel A: Y(bf16) = Xb @ Wb^T + bias (blockIdx.z selects weight).
// 128x128 tile, BK=32, global_load_lds x16, 16x16x32 bf16 MFMA, fp32 acc.
// launch_bounds(256,3): 3 wgs/CU co-resident (grid = 768 = 3/CU exactly);
// 136 regs/wave * 3 waves/SIMD = 408 <= 512, no spill.
// ---------------------------------------------------------------------------
__global__ __launch_bounds__(256, 3) void qkv_gemm_mfma(
    const unsigned short* __restrict__ Xb,
    const unsigned short* __restrict__ Wb,
    const float* __restrict__ bq, const float* __restrict__ bk,
    const float* __restrict__ bv,
    unsigned short* __restrict__ qkv)
{
    const int which = blockIdx.z;
    const unsigned short* __restrict__ W = Wb + (size_t)which * (1024 * 1024);
    const float* __restrict__ bias = (which == 0) ? bq : (which == 1) ? bk : bv;
    unsigned short* __restrict__ Y = qkv + (size_t)which * ((size_t)N_ROWS * E_DIM);

    __shared__ __align__(16) unsigned short Als[128 * 32];
    __shared__ __align__(16) unsigned short Bls[128 * 32];

    const int tid  = threadIdx.x;
    const int w    = tid >> 6;
    const int lane = tid & 63;
    const int m0 = blockIdx.x * 128;
    const int n0 = blockIdx.y * 128;
    const int wm = (w >> 1) * 64;
    const int wn = (w & 1) * 64;

    f32x4 acc[4][4];
    #pragma unroll
    for (int i = 0; i < 4; ++i)
        #pragma unroll
        for (int j = 0; j < 4; ++j)
            acc[i][j] = f32x4{0.f, 0.f, 0.f, 0.f};

    const int srow = w * 32 + (lane >> 2);
    const int skc  = (lane & 3) * 8;
    const int kq   = (lane >> 4) * 8;
    const int fm   = lane & 15;

    for (int k0 = 0; k0 < E_DIM; k0 += 32) {
        gl_lds16((const void*)(Xb + (size_t)(m0 + srow) * E_DIM + k0 + skc),
                 (void*)((char*)Als + (w * 2 + 0) * 1024));
        gl_lds16((const void*)(Xb + (size_t)(m0 + srow + 16) * E_DIM + k0 + skc),
                 (void*)((char*)Als + (w * 2 + 1) * 1024));
        gl_lds16((const void*)(W + (size_t)(n0 + srow) * E_DIM + k0 + skc),
                 (void*)((char*)Bls + (w * 2 + 0) * 1024));
        gl_lds16((const void*)(W + (size_t)(n0 + srow + 16) * E_DIM + k0 + skc),
                 (void*)((char*)Bls + (w * 2 + 1) * 1024));
        __syncthreads();

        bf16x8 af[4], bf[4];
        #pragma unroll
        for (int t = 0; t < 4; ++t) {
            af[t] = *(const bf16x8*)(Als + (wm + t * 16 + fm) * 32 + kq);
            bf[t] = *(const bf16x8*)(Bls + (wn + t * 16 + fm) * 32 + kq);
        }
        #pragma unroll
        for (int rt = 0; rt < 4; ++rt)
            #pragma unroll
            for (int ct = 0; ct < 4; ++ct)
                acc[rt][ct] = __builtin_amdgcn_mfma_f32_16x16x32_bf16(
                    af[rt], bf[ct], acc[rt][ct], 0, 0, 0);
        __syncthreads();
    }

    float bcol[4];
    #pragma unroll
    for (int ct = 0; ct < 4; ++ct) bcol[ct] = bias[n0 + wn + ct * 16 + fm];

    const int rbase = (lane >> 4) * 4;
    #pragma unroll
    for (int rt = 0; rt < 4; ++rt) {
        #pragma unroll
        for (int ct = 0; ct < 4; ++ct) {
            #pragma unroll
            for (int r = 0; r < 4; ++r) {
                const int row = m0 + wm + rt * 16 + rbase + r;
                const int col = n0 + wn + ct * 16 + fm;
                Y[(size_t)row * E_DIM + col] = f2b(acc[rt][ct][r] + bcol[ct]);
            }
        }
    }
}

// ---------------------------------------------------------------------------
// Kernel B: partial T: block (i, c): 128-row chunk:
//   P[i*16+c][e*64+d] = sum_{r in chunk} K[i][r][e] * V[i][r][d]   (fp32)
// ---------------------------------------------------------------------------
__global__ __launch_bounds__(256) void kT_partial(
    const unsigned short* __restrict__ qkv, float* __restrict__ P)
{
    const size_t base = (size_t)blockIdx.x * (2048 * 64) + (size_t)blockIdx.y * (128 * 64);
    const unsigned short* __restrict__ Kb = qkv + KB_U + base;
    const unsigned short* __restrict__ Vb = qkv + VB_U + base;
    float* __restrict__ Pout = P + ((size_t)blockIdx.x * 16 + blockIdx.y) * 4096;

    __shared__ float Ks[32][64];
    __shared__ float Vs[32][64];

    const int tid = threadIdx.x;
    const int d  = tid & 63;
    const int eg = tid >> 6;

    float acc[16];
    #pragma unroll
    for (int j = 0; j < 16; ++j) acc[j] = 0.0f;

    const int sr = tid >> 3;        // 0..31
    const int sc = (tid & 7) * 8;   // elem col

    for (int rc = 0; rc < 128; rc += 32) {
        const uint4 ku = *(const uint4*)(Kb + (size_t)(rc + sr) * 64 + sc);
        const uint4 vu = *(const uint4*)(Vb + (size_t)(rc + sr) * 64 + sc);
        Ks[sr][sc + 0] = blo(ku.x); Ks[sr][sc + 1] = bhi(ku.x);
        Ks[sr][sc + 2] = blo(ku.y); Ks[sr][sc + 3] = bhi(ku.y);
        Ks[sr][sc + 4] = blo(ku.z); Ks[sr][sc + 5] = bhi(ku.z);
        Ks[sr][sc + 6] = blo(ku.w); Ks[sr][sc + 7] = bhi(ku.w);
        Vs[sr][sc + 0] = blo(vu.x); Vs[sr][sc + 1] = bhi(vu.x);
        Vs[sr][sc + 2] = blo(vu.y); Vs[sr][sc + 3] = bhi(vu.y);
        Vs[sr][sc + 4] = blo(vu.z); Vs[sr][sc + 5] = bhi(vu.z);
        Vs[sr][sc + 6] = blo(vu.w); Vs[sr][sc + 7] = bhi(vu.w);
        __syncthreads();
        #pragma unroll
        for (int r = 0; r < 32; ++r) {
            const float v = Vs[r][d];
            #pragma unroll
            for (int j = 0; j < 16; ++j)
                acc[j] = fmaf(Ks[r][eg * 16 + j], v, acc[j]);
        }
        __syncthreads();
    }
    #pragma unroll
    for (int j = 0; j < 16; ++j)
        Pout[(size_t)(eg * 16 + j) * 64 + d] = acc[j];
}

// ---------------------------------------------------------------------------
// Kernel C0: reduce 16 partials -> Tt bf16, transposed: TB[i][d][e]
// ---------------------------------------------------------------------------
__global__ __launch_bounds__(256) void reduce_T(
    const float* __restrict__ P, unsigned short* __restrict__ TB)
{
    const int idx = blockIdx.x * 256 + threadIdx.x;  // 0..131071
    const int i   = idx >> 12;
    const int off = idx & 4095;          // e*64 + d
    const float* p = P + (size_t)i * 16 * 4096 + off;
    float s = 0.0f;
    #pragma unroll
    for (int c = 0; c < 16; ++c) s += p[(size_t)c * 4096];
    const int e = off >> 6, d = off & 63;
    TB[(size_t)i * 4096 + d * 64 + e] = f2b(s);
}

// ---------------------------------------------------------------------------
// Kernel C: out = 0.125 * Qflat @ Tt^T  (MFMA mini-GEMM, K=64).
// ---------------------------------------------------------------------------
__global__ __launch_bounds__(256, 2) void qT_mfma(
    const unsigned short* __restrict__ qkv,
    const unsigned short* __restrict__ TB,
    float* __restrict__ out)
{
    __shared__ __align__(16) unsigned short Als[128 * 64];  // 16 KB: Q rows
    __shared__ __align__(16) unsigned short Bls[64 * 64];   //  8 KB: Tt rows

    const int bx   = blockIdx.x;        // 0..511
    const int r0   = bx * 128;          // flat row base
    const int i    = bx >> 4;           // attention block
    const int tid  = threadIdx.x;
    const int w    = tid >> 6;
    const int lane = tid & 63;
    const int kq   = (lane >> 4) * 8;
    const int fm   = lane & 15;

    const unsigned short* __restrict__ Qb = qkv + QB_U + (size_t)r0 * 64;
    const unsigned short* __restrict__ Tb = TB + (size_t)i * 4096;

    #pragma unroll
    for (int c = 0; c < 4; ++c)
        gl_lds16((const void*)(Qb + (w * 4 + c) * 512 + lane * 8),
                 (void*)((char*)Als + (w * 4 + c) * 1024));
    #pragma unroll
    for (int c = 0; c < 2; ++c)
        gl_lds16((const void*)(Tb + (w * 2 + c) * 512 + lane * 8),
                 (void*)((char*)Bls + (w * 2 + c) * 1024));
    __syncthreads();

    bf16x8 af[2][2], bf[4][2];
    #pragma unroll
    for (int mt = 0; mt < 2; ++mt)
        #pragma unroll
        for (int kk = 0; kk < 2; ++kk)
            af[mt][kk] = *(const bf16x8*)(Als + (w * 32 + mt * 16 + fm) * 64 + kk * 32 + kq);
    #pragma unroll
    for (int nt = 0; nt < 4; ++nt)
        #pragma unroll
        for (int kk = 0; kk < 2; ++kk)
            bf[nt][kk] = *(const bf16x8*)(Bls + (nt * 16 + fm) * 64 + kk * 32 + kq);

    f32x4 acc[2][4];
    #pragma unroll
    for (int mt = 0; mt < 2; ++mt)
        #pragma unroll
        for (int nt = 0; nt < 4; ++nt)
            acc[mt][nt] = f32x4{0.f, 0.f, 0.f, 0.f};

    #pragma unroll
    for (int kk = 0; kk < 2; ++kk)
        #pragma unroll
        for (int mt = 0; mt < 2; ++mt)
            #pragma unroll
            for (int nt = 0; nt < 4; ++nt)
                acc[mt][nt] = __builtin_amdgcn_mfma_f32_16x16x32_bf16(
                    af[mt][kk], bf[nt][kk], acc[mt][nt], 0, 0, 0);

    const int rbase = (lane >> 4) * 4;
    #pragma unroll
    for (int mt = 0; mt < 2; ++mt) {
        #pragma unroll
        for (int nt = 0; nt < 4; ++nt) {
            #pragma unroll
            for (int r = 0; r < 4; ++r) {
                const int row = r0 + w * 32 + mt * 16 + rbase + r;
                const int col = nt * 16 + fm;
                out[(size_t)row * 64 + col] = 0.125f * acc[mt][nt][r];
            }
        }
    }
}

extern "C" void kernel_launch(void* const* d_in, const int* in_sizes, int n_in,
                              void* d_out, int out_size, void* d_ws, size_t ws_size,
                              hipStream_t stream)
{
    const float* x  = (const float*)d_in[0];
    const float* Wq = (const float*)d_in[1];
    const float* bq = (const float*)d_in[2];
    const float* Wk = (const float*)d_in[3];
    const float* bk = (const float*)d_in[4];
    const float* Wv = (const float*)d_in[5];
    const float* bv = (const float*)d_in[6];
    float* wsf = (float*)d_ws;
    unsigned short* wsu = (unsigned short*)d_ws;
    float* out = (float*)d_out;

    dim3 gCvt(512, 7);
    cvt_bf16<<<gCvt, 256, 0, stream>>>(x, Wq, Wk, Wv, wsu + XB_U);

    dim3 gA(N_ROWS / 128, E_DIM / 128, 3);   // 32 x 8 x 3
    qkv_gemm_mfma<<<gA, 256, 0, stream>>>(wsu + XB_U, wsu + WB_U,
                                          bq, bk, bv, wsu + QB_U);

    dim3 gB(32, 16);
    kT_partial<<<gB, 256, 0, stream>>>(wsu, wsf + P_F);

    reduce_T<<<512, 256, 0, stream>>>(wsf + P_F, wsu + TB_U);

    qT_mfma<<<512, 256, 0, stream>>>(wsu, wsu + TB_U, out);
}

// Round 7
// 130.505 us; speedup vs baseline: 3.3356x; 1.0548x over previous
//
#include <hip/hip_runtime.h>
#include <hip/hip_bf16.h>

// out = (Q K^T) V * scale, softmax discarded => associativity:
//   out_i = Q_i @ (K_i^T @ V_i) * scale over 32 blocks of 2048 flat rows of
//   the (65536,64) view of the (4096,1024) projections.
// R7: kT stage moved to MFMA (was LDS-bound VALU, ~25us): stage K/V chunks
// transposed in LDS, T'[d][e] = sum_r Vt[d][r]*Kt[e][r] via 16x16x32 bf16.
// Partials land in Tt orientation -> reduce_T is a straight sum, no transpose.

#define E_DIM 1024
#define N_ROWS 4096

typedef __attribute__((ext_vector_type(8))) short bf16x8;
typedef __attribute__((ext_vector_type(4))) float f32x4;

// ---- ws layout (bytes) ----
// QB [0,8.4M) KB [8.4,16.8M) VB [16.8,25.2M) bf16
// XB [25.2,33.6M) WB [33.6,39.8M) bf16
// P  [39.8,48.2M) fp32 (32 blk x 16 chunks x 4096, [d][e] orientation)
// TB [48.2,48.5M) bf16 Tt[32][d=64][e=64]
#define QB_U 0
#define KB_U 4194304
#define VB_U 8388608
#define XB_U 12582912
#define WB_U 16777216
#define P_F  9961472
#define TB_U 24117248

__device__ __forceinline__ unsigned short f2b(float f) {
    union { float f; unsigned int i; } c; c.f = f;
    unsigned int r = c.i + 0x7FFFu + ((c.i >> 16) & 1u);   // RNE (finite data)
    return (unsigned short)(r >> 16);
}

typedef __attribute__((address_space(1))) const void* gptr_t;
typedef __attribute__((address_space(3))) void* lptr_t;
__device__ __forceinline__ void gl_lds16(const void* g, void* l) {
    __builtin_amdgcn_global_load_lds((gptr_t)g, (lptr_t)l, 16, 0, 0);
}

// ---------------------------------------------------------------------------
// Kernel 0: fp32 -> bf16 convert: x (4 MB-segs) + Wq/Wk/Wv.
// ---------------------------------------------------------------------------
__global__ __launch_bounds__(256) void cvt_bf16(
    const float* __restrict__ x,  const float* __restrict__ wq,
    const float* __restrict__ wk, const float* __restrict__ wv,
    unsigned short* __restrict__ dst0)
{
    const int seg = blockIdx.y;
    const float* __restrict__ src;
    unsigned short* __restrict__ dst;
    if (seg < 4) { src = x + (size_t)seg * 1048576; dst = dst0 + (size_t)seg * 1048576; }
    else {
        src = (seg == 4) ? wq : (seg == 5) ? wk : wv;
        dst = dst0 + 4194304 + (size_t)(seg - 4) * 1048576;
    }
    const int i = blockIdx.x * 256 + threadIdx.x;   // 0..131071
    const float4 a = *(const float4*)(src + (size_t)i * 8);
    const float4 b = *(const float4*)(src + (size_t)i * 8 + 4);
    uint4 o;
    o.x = (unsigned)f2b(a.x) | ((unsigned)f2b(a.y) << 16);
    o.y = (unsigned)f2b(a.z) | ((unsigned)f2b(a.w) << 16);
    o.z = (unsigned)f2b(b.x) | ((unsigned)f2b(b.y) << 16);
    o.w = (unsigned)f2b(b.z) | ((unsigned)f2b(b.w) << 16);
    *(uint4*)(dst + (size_t)i * 8) = o;
}

// ---------------------------------------------------------------------------
// Kernel A: Y(bf16) = Xb @ Wb^T + bias (blockIdx.z selects weight).
// 128x128 tile, BK=32, global_load_lds x16, 16x16x32 bf16 MFMA, fp32 acc.
// ---------------------------------------------------------------------------
__global__ __launch_bounds__(256, 3) void qkv_gemm_mfma(
    const unsigned short* __restrict__ Xb,
    const unsigned short* __restrict__ Wb,
    const float* __restrict__ bq, const float* __restrict__ bk,
    const float* __restrict__ bv,
    unsigned short* __restrict__ qkv)
{
    const int which = blockIdx.z;
    const unsigned short* __restrict__ W = Wb + (size_t)which * (1024 * 1024);
    const float* __restrict__ bias = (which == 0) ? bq : (which == 1) ? bk : bv;
    unsigned short* __restrict__ Y = qkv + (size_t)which * ((size_t)N_ROWS * E_DIM);

    __shared__ __align__(16) unsigned short Als[128 * 32];
    __shared__ __align__(16) unsigned short Bls[128 * 32];

    const int tid  = threadIdx.x;
    const int w    = tid >> 6;
    const int lane = tid & 63;
    const int m0 = blockIdx.x * 128;
    const int n0 = blockIdx.y * 128;
    const int wm = (w >> 1) * 64;
    const int wn = (w & 1) * 64;

    f32x4 acc[4][4];
    #pragma unroll
    for (int i = 0; i < 4; ++i)
        #pragma unroll
        for (int j = 0; j < 4; ++j)
            acc[i][j] = f32x4{0.f, 0.f, 0.f, 0.f};

    const int srow = w * 32 + (lane >> 2);
    const int skc  = (lane & 3) * 8;
    const int kq   = (lane >> 4) * 8;
    const int fm   = lane & 15;

    for (int k0 = 0; k0 < E_DIM; k0 += 32) {
        gl_lds16((const void*)(Xb + (size_t)(m0 + srow) * E_DIM + k0 + skc),
                 (void*)((char*)Als + (w * 2 + 0) * 1024));
        gl_lds16((const void*)(Xb + (size_t)(m0 + srow + 16) * E_DIM + k0 + skc),
                 (void*)((char*)Als + (w * 2 + 1) * 1024));
        gl_lds16((const void*)(W + (size_t)(n0 + srow) * E_DIM + k0 + skc),
                 (void*)((char*)Bls + (w * 2 + 0) * 1024));
        gl_lds16((const void*)(W + (size_t)(n0 + srow + 16) * E_DIM + k0 + skc),
                 (void*)((char*)Bls + (w * 2 + 1) * 1024));
        __syncthreads();

        bf16x8 af[4], bf[4];
        #pragma unroll
        for (int t = 0; t < 4; ++t) {
            af[t] = *(const bf16x8*)(Als + (wm + t * 16 + fm) * 32 + kq);
            bf[t] = *(const bf16x8*)(Bls + (wn + t * 16 + fm) * 32 + kq);
        }
        #pragma unroll
        for (int rt = 0; rt < 4; ++rt)
            #pragma unroll
            for (int ct = 0; ct < 4; ++ct)
                acc[rt][ct] = __builtin_amdgcn_mfma_f32_16x16x32_bf16(
                    af[rt], bf[ct], acc[rt][ct], 0, 0, 0);
        __syncthreads();
    }

    float bcol[4];
    #pragma unroll
    for (int ct = 0; ct < 4; ++ct) bcol[ct] = bias[n0 + wn + ct * 16 + fm];

    const int rbase = (lane >> 4) * 4;
    #pragma unroll
    for (int rt = 0; rt < 4; ++rt) {
        #pragma unroll
        for (int ct = 0; ct < 4; ++ct) {
            #pragma unroll
            for (int r = 0; r < 4; ++r) {
                const int row = m0 + wm + rt * 16 + rbase + r;
                const int col = n0 + wn + ct * 16 + fm;
                Y[(size_t)row * E_DIM + col] = f2b(acc[rt][ct][r] + bcol[ct]);
            }
        }
    }
}

// ---------------------------------------------------------------------------
// Kernel B: kT via MFMA. Block (i, c): 128-row chunk of attention block i.
//   Ppart[d][e] = sum_{r in chunk} V[r][d] * K[r][e]
// Stage K,V 64-row sub-chunks TRANSPOSED in LDS (Kt[e][r], Vt[d][r]); then
// D[m=d][n=e] = sum_k A[m][k] B[n][k] with A=Vt rows, B=Kt rows (verified
// fragment pattern from qT_mfma). Wave w owns d-strip [16w,16w+16).
// ---------------------------------------------------------------------------
__global__ __launch_bounds__(256) void kT_mfma(
    const unsigned short* __restrict__ qkv, float* __restrict__ P)
{
    const size_t base = (size_t)blockIdx.x * (2048 * 64) + (size_t)blockIdx.y * (128 * 64);
    const unsigned short* __restrict__ Kb = qkv + KB_U + base;
    const unsigned short* __restrict__ Vb = qkv + VB_U + base;
    float* __restrict__ Pout = P + ((size_t)blockIdx.x * 16 + blockIdx.y) * 4096;

    __shared__ __align__(16) unsigned short Kt[64 * 64];  // [e][r] 8 KB
    __shared__ __align__(16) unsigned short Vt[64 * 64];  // [d][r] 8 KB

    const int tid  = threadIdx.x;
    const int w    = tid >> 6;
    const int lane = tid & 63;
    const int rl   = tid & 63;        // row within 64-chunk (lane)
    const int eo   = (tid >> 6) * 16; // 16-elem column group (per wave)
    const int kq   = (lane >> 4) * 8;
    const int fm   = lane & 15;

    f32x4 acc[4];
    #pragma unroll
    for (int nt = 0; nt < 4; ++nt) acc[nt] = f32x4{0.f, 0.f, 0.f, 0.f};

    for (int rb = 0; rb < 128; rb += 64) {
        // load rows rb+rl, elems [eo, eo+16) of K and V (registers)
        union { uint4 u; unsigned short s[8]; } k0, k1, v0, v1;
        const size_t ga = (size_t)(rb + rl) * 64 + eo;
        k0.u = *(const uint4*)(Kb + ga);
        k1.u = *(const uint4*)(Kb + ga + 8);
        v0.u = *(const uint4*)(Vb + ga);
        v1.u = *(const uint4*)(Vb + ga + 8);
        __syncthreads();   // previous round's fragment reads done
        #pragma unroll
        for (int j = 0; j < 8; ++j) {
            Kt[(eo + j) * 64 + rl]     = k0.s[j];
            Kt[(eo + 8 + j) * 64 + rl] = k1.s[j];
            Vt[(eo + j) * 64 + rl]     = v0.s[j];
            Vt[(eo + 8 + j) * 64 + rl] = v1.s[j];
        }
        __syncthreads();
        #pragma unroll
        for (int kk = 0; kk < 2; ++kk) {
            const bf16x8 af = *(const bf16x8*)(Vt + (w * 16 + fm) * 64 + kk * 32 + kq);
            #pragma unroll
            for (int nt = 0; nt < 4; ++nt) {
                const bf16x8 bf = *(const bf16x8*)(Kt + (nt * 16 + fm) * 64 + kk * 32 + kq);
                acc[nt] = __builtin_amdgcn_mfma_f32_16x16x32_bf16(af, bf, acc[nt], 0, 0, 0);
            }
        }
    }

    // write partial, already [d][e]: d = w*16 + (lane>>4)*4 + r, e = nt*16+fm
    const int rbase = (lane >> 4) * 4;
    #pragma unroll
    for (int nt = 0; nt < 4; ++nt)
        #pragma unroll
        for (int r = 0; r < 4; ++r)
            Pout[(size_t)(w * 16 + rbase + r) * 64 + nt * 16 + fm] = acc[nt][r];
}

// ---------------------------------------------------------------------------
// Kernel C0: reduce 16 partials -> Tt bf16: TB[i][d][e] (no transpose needed)
// ---------------------------------------------------------------------------
__global__ __launch_bounds__(256) void reduce_T(
    const float* __restrict__ P, unsigned short* __restrict__ TB)
{
    const int idx = blockIdx.x * 256 + threadIdx.x;  // 0..131071
    const int i   = idx >> 12;
    const int off = idx & 4095;          // d*64 + e
    const float* p = P + (size_t)i * 16 * 4096 + off;
    float s = 0.0f;
    #pragma unroll
    for (int c = 0; c < 16; ++c) s += p[(size_t)c * 4096];
    TB[(size_t)i * 4096 + off] = f2b(s);
}

// ---------------------------------------------------------------------------
// Kernel C: out = 0.125 * Qflat @ Tt^T  (MFMA mini-GEMM, K=64).
// ---------------------------------------------------------------------------
__global__ __launch_bounds__(256, 2) void qT_mfma(
    const unsigned short* __restrict__ qkv,
    const unsigned short* __restrict__ TB,
    float* __restrict__ out)
{
    __shared__ __align__(16) unsigned short Als[128 * 64];  // 16 KB: Q rows
    __shared__ __align__(16) unsigned short Bls[64 * 64];   //  8 KB: Tt rows

    const int bx   = blockIdx.x;        // 0..511
    const int r0   = bx * 128;          // flat row base
    const int i    = bx >> 4;           // attention block
    const int tid  = threadIdx.x;
    const int w    = tid >> 6;
    const int lane = tid & 63;
    const int kq   = (lane >> 4) * 8;
    const int fm   = lane & 15;

    const unsigned short* __restrict__ Qb = qkv + QB_U + (size_t)r0 * 64;
    const unsigned short* __restrict__ Tb = TB + (size_t)i * 4096;

    #pragma unroll
    for (int c = 0; c < 4; ++c)
        gl_lds16((const void*)(Qb + (w * 4 + c) * 512 + lane * 8),
                 (void*)((char*)Als + (w * 4 + c) * 1024));
    #pragma unroll
    for (int c = 0; c < 2; ++c)
        gl_lds16((const void*)(Tb + (w * 2 + c) * 512 + lane * 8),
                 (void*)((char*)Bls + (w * 2 + c) * 1024));
    __syncthreads();

    bf16x8 af[2][2], bf[4][2];
    #pragma unroll
    for (int mt = 0; mt < 2; ++mt)
        #pragma unroll
        for (int kk = 0; kk < 2; ++kk)
            af[mt][kk] = *(const bf16x8*)(Als + (w * 32 + mt * 16 + fm) * 64 + kk * 32 + kq);
    #pragma unroll
    for (int nt = 0; nt < 4; ++nt)
        #pragma unroll
        for (int kk = 0; kk < 2; ++kk)
            bf[nt][kk] = *(const bf16x8*)(Bls + (nt * 16 + fm) * 64 + kk * 32 + kq);

    f32x4 acc[2][4];
    #pragma unroll
    for (int mt = 0; mt < 2; ++mt)
        #pragma unroll
        for (int nt = 0; nt < 4; ++nt)
            acc[mt][nt] = f32x4{0.f, 0.f, 0.f, 0.f};

    #pragma unroll
    for (int kk = 0; kk < 2; ++kk)
        #pragma unroll
        for (int mt = 0; mt < 2; ++mt)
            #pragma unroll
            for (int nt = 0; nt < 4; ++nt)
                acc[mt][nt] = __builtin_amdgcn_mfma_f32_16x16x32_bf16(
                    af[mt][kk], bf[nt][kk], acc[mt][nt], 0, 0, 0);

    const int rbase = (lane >> 4) * 4;
    #pragma unroll
    for (int mt = 0; mt < 2; ++mt) {
        #pragma unroll
        for (int nt = 0; nt < 4; ++nt) {
            #pragma unroll
            for (int r = 0; r < 4; ++r) {
                const int row = r0 + w * 32 + mt * 16 + rbase + r;
                const int col = nt * 16 + fm;
                out[(size_t)row * 64 + col] = 0.125f * acc[mt][nt][r];
            }
        }
    }
}

extern "C" void kernel_launch(void* const* d_in, const int* in_sizes, int n_in,
                              void* d_out, int out_size, void* d_ws, size_t ws_size,
                              hipStream_t stream)
{
    const float* x  = (const float*)d_in[0];
    const float* Wq = (const float*)d_in[1];
    const float* bq = (const float*)d_in[2];
    const float* Wk = (const float*)d_in[3];
    const float* bk = (const float*)d_in[4];
    const float* Wv = (const float*)d_in[5];
    const float* bv = (const float*)d_in[6];
    float* wsf = (float*)d_ws;
    unsigned short* wsu = (unsigned short*)d_ws;
    float* out = (float*)d_out;

    dim3 gCvt(512, 7);
    cvt_bf16<<<gCvt, 256, 0, stream>>>(x, Wq, Wk, Wv, wsu + XB_U);

    dim3 gA(N_ROWS / 128, E_DIM / 128, 3);   // 32 x 8 x 3
    qkv_gemm_mfma<<<gA, 256, 0, stream>>>(wsu + XB_U, wsu + WB_U,
                                          bq, bk, bv, wsu + QB_U);

    dim3 gB(32, 16);
    kT_mfma<<<gB, 256, 0, stream>>>(wsu, wsf + P_F);

    reduce_T<<<512, 256, 0, stream>>>(wsf + P_F, wsu + TB_U);

    qT_mfma<<<512, 256, 0, stream>>>(wsu, wsu + TB_U, out);
}

// Round 8
// 130.130 us; speedup vs baseline: 3.3452x; 1.0029x over previous
//
#include <hip/hip_runtime.h>
#include <hip/hip_bf16.h>

// out = (Q K^T) V * scale, softmax discarded => associativity:
//   out_i = Q_i @ (K_i^T @ V_i) * scale over 32 blocks of 2048 flat rows of
//   the (65536,64) view of the (4096,1024) projections.
// R8: XOR-swizzled LDS layouts to kill fragment-read bank conflicts
// (GEMM was 8-way, kT/qT 16-way); kT partial chunks 16->8.

#define E_DIM 1024
#define N_ROWS 4096

typedef __attribute__((ext_vector_type(8))) short bf16x8;
typedef __attribute__((ext_vector_type(4))) float f32x4;

// ---- ws layout (bytes) ----
// QB [0,8.4M) KB [8.4,16.8M) VB [16.8,25.2M) bf16
// XB [25.2,33.6M) WB [33.6,39.8M) bf16
// P  [39.8,44M) fp32 (32 blk x 8 chunks x 4096, [d][e])
// TB [48.2,48.5M) bf16 Tt[32][d=64][e=64]
#define QB_U 0
#define KB_U 4194304
#define VB_U 8388608
#define XB_U 12582912
#define WB_U 16777216
#define P_F  9961472
#define TB_U 24117248

__device__ __forceinline__ unsigned short f2b(float f) {
    union { float f; unsigned int i; } c; c.f = f;
    unsigned int r = c.i + 0x7FFFu + ((c.i >> 16) & 1u);   // RNE (finite data)
    return (unsigned short)(r >> 16);
}

typedef __attribute__((address_space(1))) const void* gptr_t;
typedef __attribute__((address_space(3))) void* lptr_t;
__device__ __forceinline__ void gl_lds16(const void* g, void* l) {
    __builtin_amdgcn_global_load_lds((gptr_t)g, (lptr_t)l, 16, 0, 0);
}

// ---------------------------------------------------------------------------
// Kernel 0: fp32 -> bf16 convert: x (4 MB-segs) + Wq/Wk/Wv.
// ---------------------------------------------------------------------------
__global__ __launch_bounds__(256) void cvt_bf16(
    const float* __restrict__ x,  const float* __restrict__ wq,
    const float* __restrict__ wk, const float* __restrict__ wv,
    unsigned short* __restrict__ dst0)
{
    const int seg = blockIdx.y;
    const float* __restrict__ src;
    unsigned short* __restrict__ dst;
    if (seg < 4) { src = x + (size_t)seg * 1048576; dst = dst0 + (size_t)seg * 1048576; }
    else {
        src = (seg == 4) ? wq : (seg == 5) ? wk : wv;
        dst = dst0 + 4194304 + (size_t)(seg - 4) * 1048576;
    }
    const int i = blockIdx.x * 256 + threadIdx.x;   // 0..131071
    const float4 a = *(const float4*)(src + (size_t)i * 8);
    const float4 b = *(const float4*)(src + (size_t)i * 8 + 4);
    uint4 o;
    o.x = (unsigned)f2b(a.x) | ((unsigned)f2b(a.y) << 16);
    o.y = (unsigned)f2b(a.z) | ((unsigned)f2b(a.w) << 16);
    o.z = (unsigned)f2b(b.x) | ((unsigned)f2b(b.y) << 16);
    o.w = (unsigned)f2b(b.z) | ((unsigned)f2b(b.w) << 16);
    *(uint4*)(dst + (size_t)i * 8) = o;
}

// ---------------------------------------------------------------------------
// Kernel A: Y(bf16) = Xb @ Wb^T + bias (blockIdx.z selects weight).
// 128x128 tile, BK=32, global_load_lds x16, 16x16x32 bf16 MFMA, fp32 acc.
// LDS swizzle: 16B-slot s of row r holds global k-chunk s ^ ((r>>1)&3)
// -> fragment reads are 2-way (free) instead of 8-way bank-conflicted.
// ---------------------------------------------------------------------------
__global__ __launch_bounds__(256, 3) void qkv_gemm_mfma(
    const unsigned short* __restrict__ Xb,
    const unsigned short* __restrict__ Wb,
    const float* __restrict__ bq, const float* __restrict__ bk,
    const float* __restrict__ bv,
    unsigned short* __restrict__ qkv)
{
    const int which = blockIdx.z;
    const unsigned short* __restrict__ W = Wb + (size_t)which * (1024 * 1024);
    const float* __restrict__ bias = (which == 0) ? bq : (which == 1) ? bk : bv;
    unsigned short* __restrict__ Y = qkv + (size_t)which * ((size_t)N_ROWS * E_DIM);

    __shared__ __align__(16) unsigned short Als[128 * 32];
    __shared__ __align__(16) unsigned short Bls[128 * 32];

    const int tid  = threadIdx.x;
    const int w    = tid >> 6;
    const int lane = tid & 63;
    const int m0 = blockIdx.x * 128;
    const int n0 = blockIdx.y * 128;
    const int wm = (w >> 1) * 64;
    const int wn = (w & 1) * 64;

    f32x4 acc[4][4];
    #pragma unroll
    for (int i = 0; i < 4; ++i)
        #pragma unroll
        for (int j = 0; j < 4; ++j)
            acc[i][j] = f32x4{0.f, 0.f, 0.f, 0.f};

    // staging: lane -> row (lane>>2) of its 16-row chunk, LDS slot lane&3;
    // fetch global k-chunk (lane&3) ^ ((lane>>3)&3)  [swizzle]
    const int srow = w * 32 + (lane >> 2);
    const int skc  = ((lane & 3) ^ ((lane >> 3) & 3)) * 8;
    const int quad = lane >> 4;
    const int fm   = lane & 15;
    const int sw2  = (fm >> 1) & 3;           // (R>>1)&3 for R = *16-mult + fm

    for (int k0 = 0; k0 < E_DIM; k0 += 32) {
        gl_lds16((const void*)(Xb + (size_t)(m0 + srow) * E_DIM + k0 + skc),
                 (void*)((char*)Als + (w * 2 + 0) * 1024));
        gl_lds16((const void*)(Xb + (size_t)(m0 + srow + 16) * E_DIM + k0 + skc),
                 (void*)((char*)Als + (w * 2 + 1) * 1024));
        gl_lds16((const void*)(W + (size_t)(n0 + srow) * E_DIM + k0 + skc),
                 (void*)((char*)Bls + (w * 2 + 0) * 1024));
        gl_lds16((const void*)(W + (size_t)(n0 + srow + 16) * E_DIM + k0 + skc),
                 (void*)((char*)Bls + (w * 2 + 1) * 1024));
        __syncthreads();

        const int slot = (quad ^ sw2) * 8;    // swizzled 8-elem slot
        bf16x8 af[4], bf[4];
        #pragma unroll
        for (int t = 0; t < 4; ++t) {
            af[t] = *(const bf16x8*)(Als + (wm + t * 16 + fm) * 32 + slot);
            bf[t] = *(const bf16x8*)(Bls + (wn + t * 16 + fm) * 32 + slot);
        }
        #pragma unroll
        for (int rt = 0; rt < 4; ++rt)
            #pragma unroll
            for (int ct = 0; ct < 4; ++ct)
                acc[rt][ct] = __builtin_amdgcn_mfma_f32_16x16x32_bf16(
                    af[rt], bf[ct], acc[rt][ct], 0, 0, 0);
        __syncthreads();
    }

    float bcol[4];
    #pragma unroll
    for (int ct = 0; ct < 4; ++ct) bcol[ct] = bias[n0 + wn + ct * 16 + fm];

    const int rbase = (lane >> 4) * 4;
    #pragma unroll
    for (int rt = 0; rt < 4; ++rt) {
        #pragma unroll
        for (int ct = 0; ct < 4; ++ct) {
            #pragma unroll
            for (int r = 0; r < 4; ++r) {
                const int row = m0 + wm + rt * 16 + rbase + r;
                const int col = n0 + wn + ct * 16 + fm;
                Y[(size_t)row * E_DIM + col] = f2b(acc[rt][ct][r] + bcol[ct]);
            }
        }
    }
}

// swizzled index into a [row][64] LDS tile (8 slots of 8 elems per row):
// slot s of row `row` holds elems (s ^ (row&7))*8 .. +8
__device__ __forceinline__ int sw_idx(int row, int r) {
    return row * 64 + (((((r) >> 3) & 7) ^ (row & 7)) << 3) + (r & 7);
}

// ---------------------------------------------------------------------------
// Kernel B: kT via MFMA. Block (i, c): 256-row chunk of attention block i.
//   Ppart[d][e] = sum_{r in chunk} V[r][d] * K[r][e]
// K,V staged TRANSPOSED+swizzled in LDS; D[m=d][n=e] = sum_k A[m][k]B[n][k].
// ---------------------------------------------------------------------------
__global__ __launch_bounds__(256) void kT_mfma(
    const unsigned short* __restrict__ qkv, float* __restrict__ P)
{
    const size_t base = (size_t)blockIdx.x * (2048 * 64) + (size_t)blockIdx.y * (256 * 64);
    const unsigned short* __restrict__ Kb = qkv + KB_U + base;
    const unsigned short* __restrict__ Vb = qkv + VB_U + base;
    float* __restrict__ Pout = P + ((size_t)blockIdx.x * 8 + blockIdx.y) * 4096;

    __shared__ __align__(16) unsigned short Kt[64 * 64];  // [e][r] swizzled
    __shared__ __align__(16) unsigned short Vt[64 * 64];  // [d][r] swizzled

    const int tid  = threadIdx.x;
    const int w    = tid >> 6;
    const int lane = tid & 63;
    const int rl   = tid & 63;        // row within 64-chunk
    const int eo   = (tid >> 6) * 16; // 16-elem column group (per wave)
    const int quad = lane >> 4;
    const int fm   = lane & 15;
    const int sw8  = fm & 7;

    f32x4 acc[4];
    #pragma unroll
    for (int nt = 0; nt < 4; ++nt) acc[nt] = f32x4{0.f, 0.f, 0.f, 0.f};

    for (int rb = 0; rb < 256; rb += 64) {
        union { uint4 u; unsigned short s[8]; } k0, k1, v0, v1;
        const size_t ga = (size_t)(rb + rl) * 64 + eo;
        k0.u = *(const uint4*)(Kb + ga);
        k1.u = *(const uint4*)(Kb + ga + 8);
        v0.u = *(const uint4*)(Vb + ga);
        v1.u = *(const uint4*)(Vb + ga + 8);
        __syncthreads();   // previous round's fragment reads done
        #pragma unroll
        for (int j = 0; j < 8; ++j) {
            Kt[sw_idx(eo + j, rl)]     = k0.s[j];
            Kt[sw_idx(eo + 8 + j, rl)] = k1.s[j];
            Vt[sw_idx(eo + j, rl)]     = v0.s[j];
            Vt[sw_idx(eo + 8 + j, rl)] = v1.s[j];
        }
        __syncthreads();
        #pragma unroll
        for (int kk = 0; kk < 2; ++kk) {
            const int slot = ((kk * 4 + quad) ^ sw8) << 3;
            const bf16x8 af = *(const bf16x8*)(Vt + (w * 16 + fm) * 64 + slot);
            #pragma unroll
            for (int nt = 0; nt < 4; ++nt) {
                const bf16x8 bf = *(const bf16x8*)(Kt + (nt * 16 + fm) * 64 + slot);
                acc[nt] = __builtin_amdgcn_mfma_f32_16x16x32_bf16(af, bf, acc[nt], 0, 0, 0);
            }
        }
    }

    // write partial [d][e]: d = w*16 + (lane>>4)*4 + r, e = nt*16+fm
    const int rbase = (lane >> 4) * 4;
    #pragma unroll
    for (int nt = 0; nt < 4; ++nt)
        #pragma unroll
        for (int r = 0; r < 4; ++r)
            Pout[(size_t)(w * 16 + rbase + r) * 64 + nt * 16 + fm] = acc[nt][r];
}

// ---------------------------------------------------------------------------
// Kernel C0: reduce 8 partials -> Tt bf16: TB[i][d][e]
// ---------------------------------------------------------------------------
__global__ __launch_bounds__(256) void reduce_T(
    const float* __restrict__ P, unsigned short* __restrict__ TB)
{
    const int idx = blockIdx.x * 256 + threadIdx.x;  // 0..131071
    const int i   = idx >> 12;
    const int off = idx & 4095;          // d*64 + e
    const float* p = P + (size_t)i * 8 * 4096 + off;
    float s = 0.0f;
    #pragma unroll
    for (int c = 0; c < 8; ++c) s += p[(size_t)c * 4096];
    TB[(size_t)i * 4096 + off] = f2b(s);
}

// ---------------------------------------------------------------------------
// Kernel C: out = 0.125 * Qflat @ Tt^T  (MFMA mini-GEMM, K=64).
// Staging via gl_lds16 with SOURCE permutation == same XOR swizzle.
// ---------------------------------------------------------------------------
__global__ __launch_bounds__(256, 2) void qT_mfma(
    const unsigned short* __restrict__ qkv,
    const unsigned short* __restrict__ TB,
    float* __restrict__ out)
{
    __shared__ __align__(16) unsigned short Als[128 * 64];  // 16 KB: Q rows
    __shared__ __align__(16) unsigned short Bls[64 * 64];   //  8 KB: Tt rows

    const int bx   = blockIdx.x;        // 0..511
    const int r0   = bx * 128;          // flat row base
    const int i    = bx >> 4;           // attention block
    const int tid  = threadIdx.x;
    const int w    = tid >> 6;
    const int lane = tid & 63;
    const int quad = lane >> 4;
    const int fm   = lane & 15;
    const int sw8  = fm & 7;

    const unsigned short* __restrict__ Qb = qkv + QB_U + (size_t)r0 * 64;
    const unsigned short* __restrict__ Tb = TB + (size_t)i * 4096;

    // lane: row8 = lane>>3 within 8-row chunk, LDS slot lane&7;
    // fetch global slot (lane&7) ^ ((lane>>3)&7)
    const int soff = (lane >> 3) * 64 + (((lane & 7) ^ ((lane >> 3) & 7)) << 3);
    #pragma unroll
    for (int c = 0; c < 4; ++c)
        gl_lds16((const void*)(Qb + (w * 4 + c) * 512 + soff),
                 (void*)((char*)Als + (w * 4 + c) * 1024));
    #pragma unroll
    for (int c = 0; c < 2; ++c)
        gl_lds16((const void*)(Tb + (w * 2 + c) * 512 + soff),
                 (void*)((char*)Bls + (w * 2 + c) * 1024));
    __syncthreads();

    bf16x8 af[2][2], bf[4][2];
    #pragma unroll
    for (int mt = 0; mt < 2; ++mt)
        #pragma unroll
        for (int kk = 0; kk < 2; ++kk)
            af[mt][kk] = *(const bf16x8*)(Als + (w * 32 + mt * 16 + fm) * 64
                                          + (((kk * 4 + quad) ^ sw8) << 3));
    #pragma unroll
    for (int nt = 0; nt < 4; ++nt)
        #pragma unroll
        for (int kk = 0; kk < 2; ++kk)
            bf[nt][kk] = *(const bf16x8*)(Bls + (nt * 16 + fm) * 64
                                          + (((kk * 4 + quad) ^ sw8) << 3));

    f32x4 acc[2][4];
    #pragma unroll
    for (int mt = 0; mt < 2; ++mt)
        #pragma unroll
        for (int nt = 0; nt < 4; ++nt)
            acc[mt][nt] = f32x4{0.f, 0.f, 0.f, 0.f};

    #pragma unroll
    for (int kk = 0; kk < 2; ++kk)
        #pragma unroll
        for (int mt = 0; mt < 2; ++mt)
            #pragma unroll
            for (int nt = 0; nt < 4; ++nt)
                acc[mt][nt] = __builtin_amdgcn_mfma_f32_16x16x32_bf16(
                    af[mt][kk], bf[nt][kk], acc[mt][nt], 0, 0, 0);

    const int rbase = (lane >> 4) * 4;
    #pragma unroll
    for (int mt = 0; mt < 2; ++mt) {
        #pragma unroll
        for (int nt = 0; nt < 4; ++nt) {
            #pragma unroll
            for (int r = 0; r < 4; ++r) {
                const int row = r0 + w * 32 + mt * 16 + rbase + r;
                const int col = nt * 16 + fm;
                out[(size_t)row * 64 + col] = 0.125f * acc[mt][nt][r];
            }
        }
    }
}

extern "C" void kernel_launch(void* const* d_in, const int* in_sizes, int n_in,
                              void* d_out, int out_size, void* d_ws, size_t ws_size,
                              hipStream_t stream)
{
    const float* x  = (const float*)d_in[0];
    const float* Wq = (const float*)d_in[1];
    const float* bq = (const float*)d_in[2];
    const float* Wk = (const float*)d_in[3];
    const float* bk = (const float*)d_in[4];
    const float* Wv = (const float*)d_in[5];
    const float* bv = (const float*)d_in[6];
    float* wsf = (float*)d_ws;
    unsigned short* wsu = (unsigned short*)d_ws;
    float* out = (float*)d_out;

    dim3 gCvt(512, 7);
    cvt_bf16<<<gCvt, 256, 0, stream>>>(x, Wq, Wk, Wv, wsu + XB_U);

    dim3 gA(N_ROWS / 128, E_DIM / 128, 3);   // 32 x 8 x 3
    qkv_gemm_mfma<<<gA, 256, 0, stream>>>(wsu + XB_U, wsu + WB_U,
                                          bq, bk, bv, wsu + QB_U);

    dim3 gB(32, 8);
    kT_mfma<<<gB, 256, 0, stream>>>(wsu, wsf + P_F);

    reduce_T<<<512, 256, 0, stream>>>(wsf + P_F, wsu + TB_U);

    qT_mfma<<<512, 256, 0, stream>>>(wsu, wsu + TB_U, out);
}